// Round 10
// baseline (241.592 us; speedup 1.0000x reference)
//
#include <hip/hip_runtime.h>
#include <math.h>

// Problem constants (B=2, N=512, C=256, OUT=256, H=4, hd=64)
#define NB    2
#define NN    512
#define CC    256
#define OUTC  256
#define HH    4
#define LN_EPS 1e-5f

// ws layout (float offsets)
#define WS_HI     0
#define WS_HJ     262144
#define WS_V      524288
#define WS_LOGITS 786432
#define WS_CROSS  2883584   // 2*512*512
#define WS_SI     3407872
#define WS_SSI    3408896
#define WS_SJ     3409920
#define WS_SSJ    3410944   // end 3411968 floats = 13.65 MB

// Fast GELU (tanh/sigmoid form): 5 VALU + v_exp_f32 + v_rcp_f32, |err| ~3e-3
__device__ __forceinline__ float gelu_fast(float x) {
    float s = x * x;
    float w = fmaf(-0.1029432f, s, -2.3022077f);
    float e = exp2f(x * w);
    return x * __builtin_amdgcn_rcpf(1.0f + e);
}

// ---------------------------------------------------------------------------
// Kernel A v2: wave-per-row, float4 weight loads + row-stats epilogue.
// grid 256 blocks x 256 thr. wave w -> row r0+w, lane l -> channels 4l..4l+3.
// Emits Si=sum(hi), SSi=sum(hi^2), Sj, SSj per row (wave-local reduce).
// ---------------------------------------------------------------------------
__global__ __launch_bounds__(256) void kA(
    const float* __restrict__ x,  const float* __restrict__ We,
    const float* __restrict__ be, const float* __restrict__ Wv,
    const float* __restrict__ bv,
    float* __restrict__ hi, float* __restrict__ hj, float* __restrict__ v,
    float* __restrict__ Si, float* __restrict__ SSi,
    float* __restrict__ Sj, float* __restrict__ SSj)
{
    __shared__ __align__(16) float xs[4][CC];
    const int r0 = blockIdx.x * 4;
    const int t  = threadIdx.x;
    #pragma unroll
    for (int k = 0; k < 4; ++k)
        xs[k][t] = x[(size_t)(r0 + k) * CC + t];
    __syncthreads();

    const int w = t >> 6, l = t & 63;
    const int r = r0 + w;
    const float* __restrict__ xrow = xs[w];
    const float4* __restrict__ We0 = (const float4*)We + l;                 // We[c][4l..]
    const float4* __restrict__ We1 = (const float4*)(We + (size_t)CC * OUTC) + l;
    const float4* __restrict__ Wv4 = (const float4*)Wv + l;

    float4 ai = {0,0,0,0}, aj = {0,0,0,0}, av = {0,0,0,0};
    #pragma unroll 4
    for (int c = 0; c < CC; ++c) {
        float xv = xrow[c];
        float4 a = We0[(size_t)c * 64];
        float4 bq = We1[(size_t)c * 64];
        float4 cq = Wv4[(size_t)c * 64];
        ai.x = fmaf(xv, a.x, ai.x); ai.y = fmaf(xv, a.y, ai.y);
        ai.z = fmaf(xv, a.z, ai.z); ai.w = fmaf(xv, a.w, ai.w);
        aj.x = fmaf(xv, bq.x, aj.x); aj.y = fmaf(xv, bq.y, aj.y);
        aj.z = fmaf(xv, bq.z, aj.z); aj.w = fmaf(xv, bq.w, aj.w);
        av.x = fmaf(xv, cq.x, av.x); av.y = fmaf(xv, cq.y, av.y);
        av.z = fmaf(xv, cq.z, av.z); av.w = fmaf(xv, cq.w, av.w);
    }
    float4 be4 = ((const float4*)be)[l];
    float4 bv4 = ((const float4*)bv)[l];
    float4 hiv = make_float4(ai.x + be4.x, ai.y + be4.y, ai.z + be4.z, ai.w + be4.w);
    float4 vv  = make_float4(av.x + bv4.x, av.y + bv4.y, av.z + bv4.z, av.w + bv4.w);

    ((float4*)hi)[(size_t)r * 64 + l] = hiv;
    ((float4*)hj)[(size_t)r * 64 + l] = aj;
    ((float4*)v )[(size_t)r * 64 + l] = vv;

    // row stats (wave-local: wave owns the whole row)
    float si = (hiv.x + hiv.y) + (hiv.z + hiv.w);
    float ssi = hiv.x * hiv.x;
    ssi = fmaf(hiv.y, hiv.y, ssi); ssi = fmaf(hiv.z, hiv.z, ssi); ssi = fmaf(hiv.w, hiv.w, ssi);
    float sj = (aj.x + aj.y) + (aj.z + aj.w);
    float ssj = aj.x * aj.x;
    ssj = fmaf(aj.y, aj.y, ssj); ssj = fmaf(aj.z, aj.z, ssj); ssj = fmaf(aj.w, aj.w, ssj);
    #pragma unroll
    for (int off = 1; off < 64; off <<= 1) {
        si  += __shfl_xor(si,  off);
        ssi += __shfl_xor(ssi, off);
        sj  += __shfl_xor(sj,  off);
        ssj += __shfl_xor(ssj, off);
    }
    if (l == 0) { Si[r] = si; SSi[r] = ssi; Sj[r] = sj; SSj[r] = ssj; }
}

// ---------------------------------------------------------------------------
// Kernel X: cross[b][i][j] = dot(hi_row_i, hj_row_j)  (32x32 tile, k=256)
// grid: 2 b x 16 x 16 = 512 blocks x 256 thr; thread owns 2x2 outputs.
// ---------------------------------------------------------------------------
#define LXP 260
__global__ __launch_bounds__(256) void kX(
    const float* __restrict__ hi, const float* __restrict__ hj,
    float* __restrict__ cross)
{
    __shared__ __align__(16) float his[32][LXP];
    __shared__ __align__(16) float hjs[32][LXP];
    const int bid = blockIdx.x;
    const int b  = bid >> 8;
    const int i0 = ((bid >> 4) & 15) * 32;
    const int j0 = (bid & 15) * 32;
    const int t  = threadIdx.x;

    const float4* srcA = (const float4*)(hi + ((size_t)b * NN + i0) * OUTC);
    const float4* srcB = (const float4*)(hj + ((size_t)b * NN + j0) * OUTC);
    #pragma unroll
    for (int k = 0; k < 8; ++k) {
        int s = k * 256 + t, row = s >> 6, c4 = s & 63;
        *(float4*)&his[row][c4 * 4] = srcA[s];
        *(float4*)&hjs[row][c4 * 4] = srcB[s];
    }
    __syncthreads();

    const int oi = (t & 15) * 2, oj = (t >> 4) * 2;
    float a00 = 0.f, a01 = 0.f, a10 = 0.f, a11 = 0.f;
    #pragma unroll 2
    for (int c4 = 0; c4 < 64; ++c4) {
        float4 A0 = *(const float4*)&his[oi    ][c4 * 4];
        float4 A1 = *(const float4*)&his[oi + 1][c4 * 4];
        float4 B0 = *(const float4*)&hjs[oj    ][c4 * 4];
        float4 B1 = *(const float4*)&hjs[oj + 1][c4 * 4];
        a00 = fmaf(A0.x, B0.x, a00); a00 = fmaf(A0.y, B0.y, a00);
        a00 = fmaf(A0.z, B0.z, a00); a00 = fmaf(A0.w, B0.w, a00);
        a01 = fmaf(A0.x, B1.x, a01); a01 = fmaf(A0.y, B1.y, a01);
        a01 = fmaf(A0.z, B1.z, a01); a01 = fmaf(A0.w, B1.w, a01);
        a10 = fmaf(A1.x, B0.x, a10); a10 = fmaf(A1.y, B0.y, a10);
        a10 = fmaf(A1.z, B0.z, a10); a10 = fmaf(A1.w, B0.w, a10);
        a11 = fmaf(A1.x, B1.x, a11); a11 = fmaf(A1.y, B1.y, a11);
        a11 = fmaf(A1.z, B1.z, a11); a11 = fmaf(A1.w, B1.w, a11);
    }
    size_t base = ((size_t)b * NN + i0 + oi) * NN + j0 + oj;
    cross[base]          = a00;
    cross[base + 1]      = a01;
    cross[base + NN]     = a10;
    cross[base + NN + 1] = a11;
}

// ---------------------------------------------------------------------------
// Kernel B v3: stats-based LN (no pass 1) + gelu + W2 dot.
// grid: 2 b x 64 itile(8) x 16 jtile(32) = 2048 blocks, 256 thr.
// mu = (Si+Sj)/256 ; E[e^2] = (SSi + 2X + SSj)/256 ; var = E[e^2]-mu^2.
// ---------------------------------------------------------------------------
#define LDP 260
__global__ __launch_bounds__(256) void kB(
    const float* __restrict__ hi,  const float* __restrict__ hj,
    const float* __restrict__ ln1g, const float* __restrict__ ln1b,
    const float* __restrict__ W2,  const float* __restrict__ b2,
    const float* __restrict__ Si,  const float* __restrict__ SSi,
    const float* __restrict__ Sj,  const float* __restrict__ SSj,
    const float* __restrict__ cross,
    float* __restrict__ logits)
{
    __shared__ __align__(16) float hjs[32][LDP];
    __shared__ __align__(16) float his[8][LDP];
    __shared__ __align__(16) float g1s[CC];
    __shared__ __align__(16) float b1s[CC];
    __shared__ __align__(16) float w2s[CC][HH];
    __shared__ __align__(16) float crs[256];
    __shared__ float sis[8], ssis[8], sjs[32], ssjs[32];

    const int bid = blockIdx.x;
    const int jt  = (bid & 15) * 32;
    const int it  = ((bid >> 4) & 63) * 8;
    const int b   = bid >> 10;
    const int t   = threadIdx.x;

    {
        const float4* src = (const float4*)(hj + (size_t)(b * NN + jt) * OUTC);
        #pragma unroll
        for (int k = 0; k < 8; ++k) {
            int s = k * 256 + t, row = s >> 6, c4 = s & 63;
            *(float4*)&hjs[row][c4 * 4] = src[s];
        }
    }
    {
        const float4* src = (const float4*)(hi + (size_t)(b * NN + it) * OUTC);
        #pragma unroll
        for (int k = 0; k < 2; ++k) {
            int s = k * 256 + t, row = s >> 6, c4 = s & 63;
            *(float4*)&his[row][c4 * 4] = src[s];
        }
    }
    g1s[t] = ln1g[t];
    b1s[t] = ln1b[t];
    #pragma unroll
    for (int k = 0; k < 4; ++k)
        ((float*)w2s)[t + 256 * k] = W2[t + 256 * k];
    crs[t] = cross[((size_t)(b * NN + it + (t >> 5))) * NN + jt + (t & 31)];
    if (t < 8)               { sis[t] = Si[b * NN + it + t];  ssis[t] = SSi[b * NN + it + t]; }
    if (t >= 64 && t < 96)   { int q = t - 64; sjs[q] = Sj[b * NN + jt + q]; ssjs[q] = SSj[b * NN + jt + q]; }
    __syncthreads();

    const int w = t >> 6, l = t & 63;
    const int il = 2 * w + (l >> 5);
    const int jl = l & 31;
    const int i = it + il;
    const int j = jt + jl;
    const float* __restrict__ hirow = &his[il][0];
    const float* __restrict__ hjrow = &hjs[jl][0];

    // LN stats from precomputed sums
    const float mu  = (sis[il] + sjs[jl]) * (1.f / 256.f);
    const float msq = fmaf(2.f, crs[(il << 5) + jl], ssis[il] + ssjs[jl]) * (1.f / 256.f);
    const float var = fmaf(-mu, mu, msq);
    const float rs  = rsqrtf(var + LN_EPS);
    const float nmurs = -mu * rs;

    // normalize -> gelu(fast) -> dot W2
    float p0 = 0.f, p1 = 0.f, p2 = 0.f, p3 = 0.f;
    #pragma unroll 4
    for (int c4 = 0; c4 < 64; ++c4) {
        float4 a  = *(const float4*)&hirow[c4 * 4];
        float4 bb = *(const float4*)&hjrow[c4 * 4];
        float4 g  = ((const float4*)g1s)[c4];
        float4 be_ = ((const float4*)b1s)[c4];
        const float4* w2r = (const float4*)&w2s[c4 * 4][0];
        {
            float n = fmaf(a.x + bb.x, rs, nmurs);
            n = fmaf(n, g.x, be_.x);
            float ge = gelu_fast(n);
            float4 wr = w2r[0];
            p0 = fmaf(ge, wr.x, p0); p1 = fmaf(ge, wr.y, p1);
            p2 = fmaf(ge, wr.z, p2); p3 = fmaf(ge, wr.w, p3);
        }
        {
            float n = fmaf(a.y + bb.y, rs, nmurs);
            n = fmaf(n, g.y, be_.y);
            float ge = gelu_fast(n);
            float4 wr = w2r[1];
            p0 = fmaf(ge, wr.x, p0); p1 = fmaf(ge, wr.y, p1);
            p2 = fmaf(ge, wr.z, p2); p3 = fmaf(ge, wr.w, p3);
        }
        {
            float n = fmaf(a.z + bb.z, rs, nmurs);
            n = fmaf(n, g.z, be_.z);
            float ge = gelu_fast(n);
            float4 wr = w2r[2];
            p0 = fmaf(ge, wr.x, p0); p1 = fmaf(ge, wr.y, p1);
            p2 = fmaf(ge, wr.z, p2); p3 = fmaf(ge, wr.w, p3);
        }
        {
            float n = fmaf(a.w + bb.w, rs, nmurs);
            n = fmaf(n, g.w, be_.w);
            float ge = gelu_fast(n);
            float4 wr = w2r[3];
            p0 = fmaf(ge, wr.x, p0); p1 = fmaf(ge, wr.y, p1);
            p2 = fmaf(ge, wr.z, p2); p3 = fmaf(ge, wr.w, p3);
        }
    }
    float4 b2v = *(const float4*)b2;
    float4 outv = make_float4(p0 + b2v.x, p1 + b2v.y, p2 + b2v.z, p3 + b2v.w);
    ((float4*)logits)[(size_t)(b * NN + i) * NN + j] = outv;
}

// ---------------------------------------------------------------------------
// Kernel C v2: softmax + PV + Wo + residual + LN2; 2 rows/block.
// grid: 2 b x 256 = 512 blocks x 256 thr (2 blocks/CU, 8 waves/CU).
// ---------------------------------------------------------------------------
__global__ __launch_bounds__(256) void kC(
    const float* __restrict__ logits, const float* __restrict__ v,
    const float* __restrict__ Wo,     const float* __restrict__ bo,
    const float* __restrict__ x,      const float* __restrict__ g2,
    const float* __restrict__ b2ln,   float* __restrict__ out)
{
    __shared__ __align__(16) float wl[2][NN * HH];   // 16 KB
    __shared__ __align__(16) float sm[2][HH][2];
    __shared__ __align__(16) float out1[2][OUTC];
    __shared__ float redb[4][2][2];

    const int bid = blockIdx.x;
    const int b   = bid >> 8;
    const int i0  = (bid & 255) * 2;
    const int t   = threadIdx.x;

    // stage 2 logits rows: 1024 float4
    {
        const float4* src = (const float4*)(logits + ((size_t)b * NN + i0) * NN * HH);
        float4* dst = (float4*)wl;
        #pragma unroll
        for (int k = 0; k < 4; ++k) dst[k * 256 + t] = src[k * 256 + t];
    }
    __syncthreads();

    // softmax stats: 8 groups (row,h) x 32 lanes
    {
        const int g = t >> 5, k = t & 31;
        const int row = g >> 2, h = g & 3;
        const float* base = wl[row] + h;
        float m = -1e30f;
        #pragma unroll
        for (int mm = 0; mm < 16; ++mm) m = fmaxf(m, base[(k + 32 * mm) * 4]);
        #pragma unroll
        for (int off = 1; off < 32; off <<= 1) m = fmaxf(m, __shfl_xor(m, off, 32));
        float ssum = 0.f;
        #pragma unroll
        for (int mm = 0; mm < 16; ++mm) ssum += __expf(base[(k + 32 * mm) * 4] - m);
        #pragma unroll
        for (int off = 1; off < 32; off <<= 1) ssum += __shfl_xor(ssum, off, 32);
        if (k == 0) { sm[row][h][0] = m; sm[row][h][1] = 1.f / ssum; }
    }
    __syncthreads();

    // normalize in place: 4096 elems
    {
        float* wlf = &wl[0][0];
        #pragma unroll 4
        for (int k = 0; k < 16; ++k) {
            int idx = t + 256 * k;
            int row = idx >> 11, h = idx & 3;
            wlf[idx] = __expf(wlf[idx] - sm[row][h][0]) * sm[row][h][1];
        }
    }
    __syncthreads();

    // PV: out1[r][c] = sum_j p[r][j][h(c)] * v[b,j,c]
    {
        const int h = t >> 6;   // wave-uniform
        float a0 = 0.f, a1 = 0.f;
        const float* vb = v + (size_t)b * NN * OUTC + t;
        const float* p0 = wl[0] + h;
        const float* p1 = wl[1] + h;
        #pragma unroll 8
        for (int j = 0; j < NN; ++j) {
            float vv = vb[(size_t)j * OUTC];
            a0 = fmaf(p0[j * 4], vv, a0);
            a1 = fmaf(p1[j * 4], vv, a1);
        }
        out1[0][t] = a0; out1[1][t] = a1;
    }
    __syncthreads();

    // Wo matvec + bias + residual + LN2 (2 rows)
    {
        float a0 = bo[t], a1 = a0;
        #pragma unroll 4
        for (int c = 0; c < OUTC; ++c) {
            float wv = Wo[(size_t)c * OUTC + t];
            a0 = fmaf(out1[0][c], wv, a0);
            a1 = fmaf(out1[1][c], wv, a1);
        }
        float r0v = a0 + x[((size_t)b * NN + i0    ) * OUTC + t];
        float r1v = a1 + x[((size_t)b * NN + i0 + 1) * OUTC + t];

        const int w = t >> 6, l = t & 63;
        float sv0 = r0v, sq0 = r0v * r0v, sv1 = r1v, sq1 = r1v * r1v;
        #pragma unroll
        for (int off = 1; off < 64; off <<= 1) {
            sv0 += __shfl_xor(sv0, off); sq0 += __shfl_xor(sq0, off);
            sv1 += __shfl_xor(sv1, off); sq1 += __shfl_xor(sq1, off);
        }
        if (l == 0) {
            redb[w][0][0] = sv0; redb[w][0][1] = sq0;
            redb[w][1][0] = sv1; redb[w][1][1] = sq1;
        }
        __syncthreads();
        float gg = g2[t], bb = b2ln[t];
        {
            float sv = redb[0][0][0] + redb[1][0][0] + redb[2][0][0] + redb[3][0][0];
            float sq = redb[0][0][1] + redb[1][0][1] + redb[2][0][1] + redb[3][0][1];
            float mu = sv * (1.f / 256.f);
            float var = sq * (1.f / 256.f) - mu * mu;
            float rsi = rsqrtf(var + LN_EPS);
            out[((size_t)b * NN + i0) * OUTC + t] = (r0v - mu) * rsi * gg + bb;
        }
        {
            float sv = redb[0][1][0] + redb[1][1][0] + redb[2][1][0] + redb[3][1][0];
            float sq = redb[0][1][1] + redb[1][1][1] + redb[2][1][1] + redb[3][1][1];
            float mu = sv * (1.f / 256.f);
            float var = sq * (1.f / 256.f) - mu * mu;
            float rsi = rsqrtf(var + LN_EPS);
            out[((size_t)b * NN + i0 + 1) * OUTC + t] = (r1v - mu) * rsi * gg + bb;
        }
    }
}

// ---------------------------------------------------------------------------
extern "C" void kernel_launch(void* const* d_in, const int* in_sizes, int n_in,
                              void* d_out, int out_size, void* d_ws, size_t ws_size,
                              hipStream_t stream) {
    (void)in_sizes; (void)n_in; (void)out_size; (void)ws_size;
    const float* x    = (const float*)d_in[0];
    const float* We   = (const float*)d_in[1];
    const float* be   = (const float*)d_in[2];
    const float* ln1g = (const float*)d_in[3];
    const float* ln1b = (const float*)d_in[4];
    const float* W2   = (const float*)d_in[5];
    const float* b2   = (const float*)d_in[6];
    const float* Wv   = (const float*)d_in[7];
    const float* bv   = (const float*)d_in[8];
    const float* Wo   = (const float*)d_in[9];
    const float* bo   = (const float*)d_in[10];
    const float* ln2g = (const float*)d_in[11];
    const float* ln2b = (const float*)d_in[12];
    float* out = (float*)d_out;

    float* ws = (float*)d_ws;
    float* hi     = ws + WS_HI;
    float* hj     = ws + WS_HJ;
    float* v      = ws + WS_V;
    float* logits = ws + WS_LOGITS;
    float* cross  = ws + WS_CROSS;
    float* Si     = ws + WS_SI;
    float* SSi    = ws + WS_SSI;
    float* Sj     = ws + WS_SJ;
    float* SSj    = ws + WS_SSJ;

    kA<<<256,  256, 0, stream>>>(x, We, be, Wv, bv, hi, hj, v, Si, SSi, Sj, SSj);
    kX<<<512,  256, 0, stream>>>(hi, hj, cross);
    kB<<<2048, 256, 0, stream>>>(hi, hj, ln1g, ln1b, W2, b2,
                                 Si, SSi, Sj, SSj, cross, logits);
    kC<<<512,  256, 0, stream>>>(logits, v, Wo, bo, x, ln2g, ln2b, out);
}

// Round 11
// 219.288 us; speedup vs baseline: 1.1017x; 1.1017x over previous
//
#include <hip/hip_runtime.h>
#include <math.h>

// Problem constants (B=2, N=512, C=256, OUT=256, H=4, hd=64)
#define NB    2
#define NN    512
#define CC    256
#define OUTC  256
#define HH    4
#define LN_EPS 1e-5f

// ws layout (float offsets)
#define WS_HI     0
#define WS_HJ     262144
#define WS_V      524288
#define WS_LOGITS 786432
#define WS_CROSS  2883584   // 2*512*512
#define WS_SI     3407872
#define WS_SSI    3408896
#define WS_SJ     3409920
#define WS_SSJ    3410944   // end 3411968 floats = 13.65 MB

// Fast GELU (tanh/sigmoid form) with RAW v_exp_f32 (args bounded, no fixup
// path needed): 5 VALU + 2 trans. |err| vs exact-erf gelu ~3e-3.
__device__ __forceinline__ float gelu_fast(float x) {
    float s = x * x;
    float w = fmaf(-0.1029432f, s, -2.3022077f);
    float e = __builtin_amdgcn_exp2f(x * w);
    return x * __builtin_amdgcn_rcpf(1.0f + e);
}

// ---------------------------------------------------------------------------
// Kernel A v3: thread-per-channel, 8 rows/block (weights loaded once per
// block, reused across 8 rows in registers -> 98 MB L2 weight traffic).
// grid 128 blocks x 256 thr. Stats via shfl + LDS block reduce.
// ---------------------------------------------------------------------------
__global__ __launch_bounds__(256) void kA(
    const float* __restrict__ x,  const float* __restrict__ We,
    const float* __restrict__ be, const float* __restrict__ Wv,
    const float* __restrict__ bv,
    float* __restrict__ hi, float* __restrict__ hj, float* __restrict__ v,
    float* __restrict__ Si, float* __restrict__ SSi,
    float* __restrict__ Sj, float* __restrict__ SSj)
{
    __shared__ __align__(16) float xs[8][CC];   // 8 KB
    __shared__ float red[4][32];
    const int r0 = blockIdx.x * 8;
    const int t  = threadIdx.x;

    {
        const float4* src = (const float4*)(x + (size_t)r0 * CC);
        #pragma unroll
        for (int k = 0; k < 2; ++k)
            ((float4*)xs)[k * 256 + t] = src[k * 256 + t];
    }
    __syncthreads();

    float hia[8] = {0,0,0,0,0,0,0,0};
    float hja[8] = {0,0,0,0,0,0,0,0};
    float va [8] = {0,0,0,0,0,0,0,0};
    #pragma unroll 4
    for (int c = 0; c < CC; ++c) {
        float we0 = We[(size_t)c * OUTC + t];
        float we1 = We[(size_t)(CC + c) * OUTC + t];
        float wv  = Wv[(size_t)c * OUTC + t];
        #pragma unroll
        for (int r = 0; r < 8; ++r) {
            float xv = xs[r][c];           // wave-uniform broadcast
            hia[r] = fmaf(xv, we0, hia[r]);
            hja[r] = fmaf(xv, we1, hja[r]);
            va [r] = fmaf(xv, wv , va [r]);
        }
    }
    float beT = be[t], bvT = bv[t];
    #pragma unroll
    for (int r = 0; r < 8; ++r) {
        hia[r] += beT;
        va [r] += bvT;
        hi[(size_t)(r0 + r) * OUTC + t] = hia[r];
        hj[(size_t)(r0 + r) * OUTC + t] = hja[r];
        v [(size_t)(r0 + r) * OUTC + t] = va [r];
    }

    // block-wide row stats: per row r: Si, SSi, Sj, SSj
    const int w = t >> 6, l = t & 63;
    float part[32];
    #pragma unroll
    for (int r = 0; r < 8; ++r) {
        part[r * 4 + 0] = hia[r];
        part[r * 4 + 1] = hia[r] * hia[r];
        part[r * 4 + 2] = hja[r];
        part[r * 4 + 3] = hja[r] * hja[r];
    }
    #pragma unroll
    for (int q = 0; q < 32; ++q) {
        float s = part[q];
        #pragma unroll
        for (int off = 1; off < 64; off <<= 1) s += __shfl_xor(s, off);
        if (l == 0) red[w][q] = s;
    }
    __syncthreads();
    if (t < 32) {
        float s = red[0][t] + red[1][t] + red[2][t] + red[3][t];
        int r = r0 + (t >> 2), st = t & 3;
        if      (st == 0) Si [r] = s;
        else if (st == 1) SSi[r] = s;
        else if (st == 2) Sj [r] = s;
        else              SSj[r] = s;
    }
}

// ---------------------------------------------------------------------------
// Kernel X: cross[b][i][j] = dot(hi_row_i, hj_row_j)  (32x32 tile, k=256)
// grid: 2 b x 16 x 16 = 512 blocks x 256 thr; thread owns 2x2 outputs.
// ---------------------------------------------------------------------------
#define LXP 260
__global__ __launch_bounds__(256) void kX(
    const float* __restrict__ hi, const float* __restrict__ hj,
    float* __restrict__ cross)
{
    __shared__ __align__(16) float his[32][LXP];
    __shared__ __align__(16) float hjs[32][LXP];
    const int bid = blockIdx.x;
    const int b  = bid >> 8;
    const int i0 = ((bid >> 4) & 15) * 32;
    const int j0 = (bid & 15) * 32;
    const int t  = threadIdx.x;

    const float4* srcA = (const float4*)(hi + ((size_t)b * NN + i0) * OUTC);
    const float4* srcB = (const float4*)(hj + ((size_t)b * NN + j0) * OUTC);
    #pragma unroll
    for (int k = 0; k < 8; ++k) {
        int s = k * 256 + t, row = s >> 6, c4 = s & 63;
        *(float4*)&his[row][c4 * 4] = srcA[s];
        *(float4*)&hjs[row][c4 * 4] = srcB[s];
    }
    __syncthreads();

    const int oi = (t & 15) * 2, oj = (t >> 4) * 2;
    float a00 = 0.f, a01 = 0.f, a10 = 0.f, a11 = 0.f;
    #pragma unroll 2
    for (int c4 = 0; c4 < 64; ++c4) {
        float4 A0 = *(const float4*)&his[oi    ][c4 * 4];
        float4 A1 = *(const float4*)&his[oi + 1][c4 * 4];
        float4 B0 = *(const float4*)&hjs[oj    ][c4 * 4];
        float4 B1 = *(const float4*)&hjs[oj + 1][c4 * 4];
        a00 = fmaf(A0.x, B0.x, a00); a00 = fmaf(A0.y, B0.y, a00);
        a00 = fmaf(A0.z, B0.z, a00); a00 = fmaf(A0.w, B0.w, a00);
        a01 = fmaf(A0.x, B1.x, a01); a01 = fmaf(A0.y, B1.y, a01);
        a01 = fmaf(A0.z, B1.z, a01); a01 = fmaf(A0.w, B1.w, a01);
        a10 = fmaf(A1.x, B0.x, a10); a10 = fmaf(A1.y, B0.y, a10);
        a10 = fmaf(A1.z, B0.z, a10); a10 = fmaf(A1.w, B0.w, a10);
        a11 = fmaf(A1.x, B1.x, a11); a11 = fmaf(A1.y, B1.y, a11);
        a11 = fmaf(A1.z, B1.z, a11); a11 = fmaf(A1.w, B1.w, a11);
    }
    size_t base = ((size_t)b * NN + i0 + oi) * NN + j0 + oj;
    cross[base]          = a00;
    cross[base + 1]      = a01;
    cross[base + NN]     = a10;
    cross[base + NN + 1] = a11;
}

// ---------------------------------------------------------------------------
// Kernel B v3.1: stats-based LN + gelu(raw exp) + W2 dot.
// grid: 2 b x 64 itile(8) x 16 jtile(32) = 2048 blocks, 256 thr.
// ---------------------------------------------------------------------------
#define LDP 260
__global__ __launch_bounds__(256) void kB(
    const float* __restrict__ hi,  const float* __restrict__ hj,
    const float* __restrict__ ln1g, const float* __restrict__ ln1b,
    const float* __restrict__ W2,  const float* __restrict__ b2,
    const float* __restrict__ Si,  const float* __restrict__ SSi,
    const float* __restrict__ Sj,  const float* __restrict__ SSj,
    const float* __restrict__ cross,
    float* __restrict__ logits)
{
    __shared__ __align__(16) float hjs[32][LDP];
    __shared__ __align__(16) float his[8][LDP];
    __shared__ __align__(16) float g1s[CC];
    __shared__ __align__(16) float b1s[CC];
    __shared__ __align__(16) float w2s[CC][HH];
    __shared__ __align__(16) float crs[256];
    __shared__ float sis[8], ssis[8], sjs[32], ssjs[32];

    const int bid = blockIdx.x;
    const int jt  = (bid & 15) * 32;
    const int it  = ((bid >> 4) & 63) * 8;
    const int b   = bid >> 10;
    const int t   = threadIdx.x;

    {
        const float4* src = (const float4*)(hj + (size_t)(b * NN + jt) * OUTC);
        #pragma unroll
        for (int k = 0; k < 8; ++k) {
            int s = k * 256 + t, row = s >> 6, c4 = s & 63;
            *(float4*)&hjs[row][c4 * 4] = src[s];
        }
    }
    {
        const float4* src = (const float4*)(hi + (size_t)(b * NN + it) * OUTC);
        #pragma unroll
        for (int k = 0; k < 2; ++k) {
            int s = k * 256 + t, row = s >> 6, c4 = s & 63;
            *(float4*)&his[row][c4 * 4] = src[s];
        }
    }
    g1s[t] = ln1g[t];
    b1s[t] = ln1b[t];
    #pragma unroll
    for (int k = 0; k < 4; ++k)
        ((float*)w2s)[t + 256 * k] = W2[t + 256 * k];
    crs[t] = cross[((size_t)(b * NN + it + (t >> 5))) * NN + jt + (t & 31)];
    if (t < 8)               { sis[t] = Si[b * NN + it + t];  ssis[t] = SSi[b * NN + it + t]; }
    if (t >= 64 && t < 96)   { int q = t - 64; sjs[q] = Sj[b * NN + jt + q]; ssjs[q] = SSj[b * NN + jt + q]; }
    __syncthreads();

    const int w = t >> 6, l = t & 63;
    const int il = 2 * w + (l >> 5);
    const int jl = l & 31;
    const int i = it + il;
    const int j = jt + jl;
    const float* __restrict__ hirow = &his[il][0];
    const float* __restrict__ hjrow = &hjs[jl][0];

    const float mu  = (sis[il] + sjs[jl]) * (1.f / 256.f);
    const float msq = fmaf(2.f, crs[(il << 5) + jl], ssis[il] + ssjs[jl]) * (1.f / 256.f);
    const float var = fmaf(-mu, mu, msq);
    const float rs  = rsqrtf(var + LN_EPS);
    const float nmurs = -mu * rs;

    float p0 = 0.f, p1 = 0.f, p2 = 0.f, p3 = 0.f;
    #pragma unroll 4
    for (int c4 = 0; c4 < 64; ++c4) {
        float4 a  = *(const float4*)&hirow[c4 * 4];
        float4 bb = *(const float4*)&hjrow[c4 * 4];
        float4 g  = ((const float4*)g1s)[c4];
        float4 be_ = ((const float4*)b1s)[c4];
        const float4* w2r = (const float4*)&w2s[c4 * 4][0];
        {
            float n = fmaf(a.x + bb.x, rs, nmurs);
            n = fmaf(n, g.x, be_.x);
            float ge = gelu_fast(n);
            float4 wr = w2r[0];
            p0 = fmaf(ge, wr.x, p0); p1 = fmaf(ge, wr.y, p1);
            p2 = fmaf(ge, wr.z, p2); p3 = fmaf(ge, wr.w, p3);
        }
        {
            float n = fmaf(a.y + bb.y, rs, nmurs);
            n = fmaf(n, g.y, be_.y);
            float ge = gelu_fast(n);
            float4 wr = w2r[1];
            p0 = fmaf(ge, wr.x, p0); p1 = fmaf(ge, wr.y, p1);
            p2 = fmaf(ge, wr.z, p2); p3 = fmaf(ge, wr.w, p3);
        }
        {
            float n = fmaf(a.z + bb.z, rs, nmurs);
            n = fmaf(n, g.z, be_.z);
            float ge = gelu_fast(n);
            float4 wr = w2r[2];
            p0 = fmaf(ge, wr.x, p0); p1 = fmaf(ge, wr.y, p1);
            p2 = fmaf(ge, wr.z, p2); p3 = fmaf(ge, wr.w, p3);
        }
        {
            float n = fmaf(a.w + bb.w, rs, nmurs);
            n = fmaf(n, g.w, be_.w);
            float ge = gelu_fast(n);
            float4 wr = w2r[3];
            p0 = fmaf(ge, wr.x, p0); p1 = fmaf(ge, wr.y, p1);
            p2 = fmaf(ge, wr.z, p2); p3 = fmaf(ge, wr.w, p3);
        }
    }
    float4 b2v = *(const float4*)b2;
    float4 outv = make_float4(p0 + b2v.x, p1 + b2v.y, p2 + b2v.z, p3 + b2v.w);
    ((float4*)logits)[(size_t)(b * NN + i) * NN + j] = outv;
}

// ---------------------------------------------------------------------------
// Kernel C v2 (unchanged): softmax + PV + Wo + residual + LN2; 2 rows/block.
// grid: 2 b x 256 = 512 blocks x 256 thr.
// ---------------------------------------------------------------------------
__global__ __launch_bounds__(256) void kC(
    const float* __restrict__ logits, const float* __restrict__ v,
    const float* __restrict__ Wo,     const float* __restrict__ bo,
    const float* __restrict__ x,      const float* __restrict__ g2,
    const float* __restrict__ b2ln,   float* __restrict__ out)
{
    __shared__ __align__(16) float wl[2][NN * HH];
    __shared__ __align__(16) float sm[2][HH][2];
    __shared__ __align__(16) float out1[2][OUTC];
    __shared__ float redb[4][2][2];

    const int bid = blockIdx.x;
    const int b   = bid >> 8;
    const int i0  = (bid & 255) * 2;
    const int t   = threadIdx.x;

    {
        const float4* src = (const float4*)(logits + ((size_t)b * NN + i0) * NN * HH);
        float4* dst = (float4*)wl;
        #pragma unroll
        for (int k = 0; k < 4; ++k) dst[k * 256 + t] = src[k * 256 + t];
    }
    __syncthreads();

    {
        const int g = t >> 5, k = t & 31;
        const int row = g >> 2, h = g & 3;
        const float* base = wl[row] + h;
        float m = -1e30f;
        #pragma unroll
        for (int mm = 0; mm < 16; ++mm) m = fmaxf(m, base[(k + 32 * mm) * 4]);
        #pragma unroll
        for (int off = 1; off < 32; off <<= 1) m = fmaxf(m, __shfl_xor(m, off, 32));
        float ssum = 0.f;
        #pragma unroll
        for (int mm = 0; mm < 16; ++mm) ssum += __expf(base[(k + 32 * mm) * 4] - m);
        #pragma unroll
        for (int off = 1; off < 32; off <<= 1) ssum += __shfl_xor(ssum, off, 32);
        if (k == 0) { sm[row][h][0] = m; sm[row][h][1] = 1.f / ssum; }
    }
    __syncthreads();

    {
        float* wlf = &wl[0][0];
        #pragma unroll 4
        for (int k = 0; k < 16; ++k) {
            int idx = t + 256 * k;
            int row = idx >> 11, h = idx & 3;
            wlf[idx] = __expf(wlf[idx] - sm[row][h][0]) * sm[row][h][1];
        }
    }
    __syncthreads();

    {
        const int h = t >> 6;
        float a0 = 0.f, a1 = 0.f;
        const float* vb = v + (size_t)b * NN * OUTC + t;
        const float* p0 = wl[0] + h;
        const float* p1 = wl[1] + h;
        #pragma unroll 8
        for (int j = 0; j < NN; ++j) {
            float vv = vb[(size_t)j * OUTC];
            a0 = fmaf(p0[j * 4], vv, a0);
            a1 = fmaf(p1[j * 4], vv, a1);
        }
        out1[0][t] = a0; out1[1][t] = a1;
    }
    __syncthreads();

    {
        float a0 = bo[t], a1 = a0;
        #pragma unroll 4
        for (int c = 0; c < OUTC; ++c) {
            float wv = Wo[(size_t)c * OUTC + t];
            a0 = fmaf(out1[0][c], wv, a0);
            a1 = fmaf(out1[1][c], wv, a1);
        }
        float r0v = a0 + x[((size_t)b * NN + i0    ) * OUTC + t];
        float r1v = a1 + x[((size_t)b * NN + i0 + 1) * OUTC + t];

        const int w = t >> 6, l = t & 63;
        float sv0 = r0v, sq0 = r0v * r0v, sv1 = r1v, sq1 = r1v * r1v;
        #pragma unroll
        for (int off = 1; off < 64; off <<= 1) {
            sv0 += __shfl_xor(sv0, off); sq0 += __shfl_xor(sq0, off);
            sv1 += __shfl_xor(sv1, off); sq1 += __shfl_xor(sq1, off);
        }
        if (l == 0) {
            redb[w][0][0] = sv0; redb[w][0][1] = sq0;
            redb[w][1][0] = sv1; redb[w][1][1] = sq1;
        }
        __syncthreads();
        float gg = g2[t], bb = b2ln[t];
        {
            float sv = redb[0][0][0] + redb[1][0][0] + redb[2][0][0] + redb[3][0][0];
            float sq = redb[0][0][1] + redb[1][0][1] + redb[2][0][1] + redb[3][0][1];
            float mu = sv * (1.f / 256.f);
            float var = sq * (1.f / 256.f) - mu * mu;
            float rsi = rsqrtf(var + LN_EPS);
            out[((size_t)b * NN + i0) * OUTC + t] = (r0v - mu) * rsi * gg + bb;
        }
        {
            float sv = redb[0][1][0] + redb[1][1][0] + redb[2][1][0] + redb[3][1][0];
            float sq = redb[0][1][1] + redb[1][1][1] + redb[2][1][1] + redb[3][1][1];
            float mu = sv * (1.f / 256.f);
            float var = sq * (1.f / 256.f) - mu * mu;
            float rsi = rsqrtf(var + LN_EPS);
            out[((size_t)b * NN + i0 + 1) * OUTC + t] = (r1v - mu) * rsi * gg + bb;
        }
    }
}

// ---------------------------------------------------------------------------
extern "C" void kernel_launch(void* const* d_in, const int* in_sizes, int n_in,
                              void* d_out, int out_size, void* d_ws, size_t ws_size,
                              hipStream_t stream) {
    (void)in_sizes; (void)n_in; (void)out_size; (void)ws_size;
    const float* x    = (const float*)d_in[0];
    const float* We   = (const float*)d_in[1];
    const float* be   = (const float*)d_in[2];
    const float* ln1g = (const float*)d_in[3];
    const float* ln1b = (const float*)d_in[4];
    const float* W2   = (const float*)d_in[5];
    const float* b2   = (const float*)d_in[6];
    const float* Wv   = (const float*)d_in[7];
    const float* bv   = (const float*)d_in[8];
    const float* Wo   = (const float*)d_in[9];
    const float* bo   = (const float*)d_in[10];
    const float* ln2g = (const float*)d_in[11];
    const float* ln2b = (const float*)d_in[12];
    float* out = (float*)d_out;

    float* ws = (float*)d_ws;
    float* hi     = ws + WS_HI;
    float* hj     = ws + WS_HJ;
    float* v      = ws + WS_V;
    float* logits = ws + WS_LOGITS;
    float* cross  = ws + WS_CROSS;
    float* Si     = ws + WS_SI;
    float* SSi    = ws + WS_SSI;
    float* Sj     = ws + WS_SJ;
    float* SSj    = ws + WS_SSJ;

    kA<<<128,  256, 0, stream>>>(x, We, be, Wv, bv, hi, hj, v, Si, SSi, Sj, SSj);
    kX<<<512,  256, 0, stream>>>(hi, hj, cross);
    kB<<<2048, 256, 0, stream>>>(hi, hj, ln1g, ln1b, W2, b2,
                                 Si, SSi, Sj, SSj, cross, logits);
    kC<<<512,  256, 0, stream>>>(logits, v, Wo, bo, x, ln2g, ln2b, out);
}

// Round 13
// 218.962 us; speedup vs baseline: 1.1033x; 1.0015x over previous
//
#include <hip/hip_runtime.h>
#include <math.h>

// Problem constants (B=2, N=512, C=256, OUT=256, H=4, hd=64)
#define NB    2
#define NN    512
#define CC    256
#define OUTC  256
#define HH    4
#define LN_EPS 1e-5f

// ws layout (float offsets)
#define WS_HI     0
#define WS_HJ     262144
#define WS_V      524288
#define WS_LOGITS 786432
#define WS_CROSS  2883584   // 2*512*512
#define WS_SI     3407872
#define WS_SSI    3408896
#define WS_SJ     3409920
#define WS_SSJ    3410944   // end 3411968 floats = 13.65 MB

// Fast GELU (tanh/sigmoid form) with RAW v_exp_f32: 5 VALU + 2 trans.
__device__ __forceinline__ float gelu_fast(float x) {
    float s = x * x;
    float w = fmaf(-0.1029432f, s, -2.3022077f);
    float e = __builtin_amdgcn_exp2f(x * w);
    return x * __builtin_amdgcn_rcpf(1.0f + e);
}

// ---------------------------------------------------------------------------
// Kernel A v3: thread-per-channel, 8 rows/block (weights reused across rows).
// grid 128 blocks x 256 thr. Stats via shfl + LDS block reduce.
// ---------------------------------------------------------------------------
__global__ __launch_bounds__(256) void kA(
    const float* __restrict__ x,  const float* __restrict__ We,
    const float* __restrict__ be, const float* __restrict__ Wv,
    const float* __restrict__ bv,
    float* __restrict__ hi, float* __restrict__ hj, float* __restrict__ v,
    float* __restrict__ Si, float* __restrict__ SSi,
    float* __restrict__ Sj, float* __restrict__ SSj)
{
    __shared__ __align__(16) float xs[8][CC];   // 8 KB
    __shared__ float red[4][32];
    const int r0 = blockIdx.x * 8;
    const int t  = threadIdx.x;

    {
        const float4* src = (const float4*)(x + (size_t)r0 * CC);
        #pragma unroll
        for (int k = 0; k < 2; ++k)
            ((float4*)xs)[k * 256 + t] = src[k * 256 + t];
    }
    __syncthreads();

    float hia[8] = {0,0,0,0,0,0,0,0};
    float hja[8] = {0,0,0,0,0,0,0,0};
    float va [8] = {0,0,0,0,0,0,0,0};
    #pragma unroll 4
    for (int c = 0; c < CC; ++c) {
        float we0 = We[(size_t)c * OUTC + t];
        float we1 = We[(size_t)(CC + c) * OUTC + t];
        float wv  = Wv[(size_t)c * OUTC + t];
        #pragma unroll
        for (int r = 0; r < 8; ++r) {
            float xv = xs[r][c];           // wave-uniform broadcast
            hia[r] = fmaf(xv, we0, hia[r]);
            hja[r] = fmaf(xv, we1, hja[r]);
            va [r] = fmaf(xv, wv , va [r]);
        }
    }
    float beT = be[t], bvT = bv[t];
    #pragma unroll
    for (int r = 0; r < 8; ++r) {
        hia[r] += beT;
        va [r] += bvT;
        hi[(size_t)(r0 + r) * OUTC + t] = hia[r];
        hj[(size_t)(r0 + r) * OUTC + t] = hja[r];
        v [(size_t)(r0 + r) * OUTC + t] = va [r];
    }

    // block-wide row stats: per row r: Si, SSi, Sj, SSj
    const int w = t >> 6, l = t & 63;
    float part[32];
    #pragma unroll
    for (int r = 0; r < 8; ++r) {
        part[r * 4 + 0] = hia[r];
        part[r * 4 + 1] = hia[r] * hia[r];
        part[r * 4 + 2] = hja[r];
        part[r * 4 + 3] = hja[r] * hja[r];
    }
    #pragma unroll
    for (int q = 0; q < 32; ++q) {
        float s = part[q];
        #pragma unroll
        for (int off = 1; off < 64; off <<= 1) s += __shfl_xor(s, off);
        if (l == 0) red[w][q] = s;
    }
    __syncthreads();
    if (t < 32) {
        float s = red[0][t] + red[1][t] + red[2][t] + red[3][t];
        int r = r0 + (t >> 2), st = t & 3;
        if      (st == 0) Si [r] = s;
        else if (st == 1) SSi[r] = s;
        else if (st == 2) Sj [r] = s;
        else              SSj[r] = s;
    }
}

// ---------------------------------------------------------------------------
// Kernel X: cross[b][i][j] = dot(hi_row_i, hj_row_j)  (32x32 tile, k=256)
// grid: 2 b x 16 x 16 = 512 blocks x 256 thr; thread owns 2x2 outputs.
// ---------------------------------------------------------------------------
#define LXP 260
__global__ __launch_bounds__(256) void kX(
    const float* __restrict__ hi, const float* __restrict__ hj,
    float* __restrict__ cross)
{
    __shared__ __align__(16) float his[32][LXP];
    __shared__ __align__(16) float hjs[32][LXP];
    const int bid = blockIdx.x;
    const int b  = bid >> 8;
    const int i0 = ((bid >> 4) & 15) * 32;
    const int j0 = (bid & 15) * 32;
    const int t  = threadIdx.x;

    const float4* srcA = (const float4*)(hi + ((size_t)b * NN + i0) * OUTC);
    const float4* srcB = (const float4*)(hj + ((size_t)b * NN + j0) * OUTC);
    #pragma unroll
    for (int k = 0; k < 8; ++k) {
        int s = k * 256 + t, row = s >> 6, c4 = s & 63;
        *(float4*)&his[row][c4 * 4] = srcA[s];
        *(float4*)&hjs[row][c4 * 4] = srcB[s];
    }
    __syncthreads();

    const int oi = (t & 15) * 2, oj = (t >> 4) * 2;
    float a00 = 0.f, a01 = 0.f, a10 = 0.f, a11 = 0.f;
    #pragma unroll 2
    for (int c4 = 0; c4 < 64; ++c4) {
        float4 A0 = *(const float4*)&his[oi    ][c4 * 4];
        float4 A1 = *(const float4*)&his[oi + 1][c4 * 4];
        float4 B0 = *(const float4*)&hjs[oj    ][c4 * 4];
        float4 B1 = *(const float4*)&hjs[oj + 1][c4 * 4];
        a00 = fmaf(A0.x, B0.x, a00); a00 = fmaf(A0.y, B0.y, a00);
        a00 = fmaf(A0.z, B0.z, a00); a00 = fmaf(A0.w, B0.w, a00);
        a01 = fmaf(A0.x, B1.x, a01); a01 = fmaf(A0.y, B1.y, a01);
        a01 = fmaf(A0.z, B1.z, a01); a01 = fmaf(A0.w, B1.w, a01);
        a10 = fmaf(A1.x, B0.x, a10); a10 = fmaf(A1.y, B0.y, a10);
        a10 = fmaf(A1.z, B0.z, a10); a10 = fmaf(A1.w, B0.w, a10);
        a11 = fmaf(A1.x, B1.x, a11); a11 = fmaf(A1.y, B1.y, a11);
        a11 = fmaf(A1.z, B1.z, a11); a11 = fmaf(A1.w, B1.w, a11);
    }
    size_t base = ((size_t)b * NN + i0 + oi) * NN + j0 + oj;
    cross[base]          = a00;
    cross[base + 1]      = a01;
    cross[base + NN]     = a10;
    cross[base + NN + 1] = a11;
}

// ---------------------------------------------------------------------------
// Kernel B v4: stats-based LN + gelu(raw exp) + W2 dot.
// g/be/W2 read via UNIFORM global loads (scalar pipe / K$) -> LDS pipe only
// carries hi/hj. grid: 2 b x 64 itile(8) x 16 jtile(32) = 2048 blocks.
// ---------------------------------------------------------------------------
#define LDP 260
__global__ __launch_bounds__(256) void kB(
    const float* __restrict__ hi,  const float* __restrict__ hj,
    const float* __restrict__ ln1g, const float* __restrict__ ln1b,
    const float* __restrict__ W2,  const float* __restrict__ b2,
    const float* __restrict__ Si,  const float* __restrict__ SSi,
    const float* __restrict__ Sj,  const float* __restrict__ SSj,
    const float* __restrict__ cross,
    float* __restrict__ logits)
{
    __shared__ __align__(16) float hjs[32][LDP];
    __shared__ __align__(16) float his[8][LDP];
    __shared__ __align__(16) float crs[256];
    __shared__ float sis[8], ssis[8], sjs[32], ssjs[32];

    const int bid = blockIdx.x;
    const int jt  = (bid & 15) * 32;
    const int it  = ((bid >> 4) & 63) * 8;
    const int b   = bid >> 10;
    const int t   = threadIdx.x;

    {
        const float4* src = (const float4*)(hj + (size_t)(b * NN + jt) * OUTC);
        #pragma unroll
        for (int k = 0; k < 8; ++k) {
            int s = k * 256 + t, row = s >> 6, c4 = s & 63;
            *(float4*)&hjs[row][c4 * 4] = src[s];
        }
    }
    {
        const float4* src = (const float4*)(hi + (size_t)(b * NN + it) * OUTC);
        #pragma unroll
        for (int k = 0; k < 2; ++k) {
            int s = k * 256 + t, row = s >> 6, c4 = s & 63;
            *(float4*)&his[row][c4 * 4] = src[s];
        }
    }
    crs[t] = cross[((size_t)(b * NN + it + (t >> 5))) * NN + jt + (t & 31)];
    if (t < 8)               { sis[t] = Si[b * NN + it + t];  ssis[t] = SSi[b * NN + it + t]; }
    if (t >= 64 && t < 96)   { int q = t - 64; sjs[q] = Sj[b * NN + jt + q]; ssjs[q] = SSj[b * NN + jt + q]; }
    __syncthreads();

    const int w = t >> 6, l = t & 63;
    const int il = 2 * w + (l >> 5);
    const int jl = l & 31;
    const int i = it + il;
    const int j = jt + jl;
    const float* __restrict__ hirow = &his[il][0];
    const float* __restrict__ hjrow = &hjs[jl][0];

    const float mu  = (sis[il] + sjs[jl]) * (1.f / 256.f);
    const float msq = fmaf(2.f, crs[(il << 5) + jl], ssis[il] + ssjs[jl]) * (1.f / 256.f);
    const float var = fmaf(-mu, mu, msq);
    const float rs  = rsqrtf(var + LN_EPS);
    const float nmurs = -mu * rs;

    // uniform-index pointers (block-invariant bases, loop-var index -> s_load)
    const float4* __restrict__ g4p  = (const float4*)ln1g;
    const float4* __restrict__ be4p = (const float4*)ln1b;
    const float4* __restrict__ w2p  = (const float4*)W2;    // row c = w2p[c]

    float p0 = 0.f, p1 = 0.f, p2 = 0.f, p3 = 0.f;
    #pragma unroll 4
    for (int c4 = 0; c4 < 64; ++c4) {
        float4 a   = *(const float4*)&hirow[c4 * 4];
        float4 bb  = *(const float4*)&hjrow[c4 * 4];
        float4 g   = g4p[c4];
        float4 be_ = be4p[c4];
        float4 wr0 = w2p[c4 * 4 + 0];
        float4 wr1 = w2p[c4 * 4 + 1];
        float4 wr2 = w2p[c4 * 4 + 2];
        float4 wr3 = w2p[c4 * 4 + 3];
        {
            float n = fmaf(a.x + bb.x, rs, nmurs);
            n = fmaf(n, g.x, be_.x);
            float ge = gelu_fast(n);
            p0 = fmaf(ge, wr0.x, p0); p1 = fmaf(ge, wr0.y, p1);
            p2 = fmaf(ge, wr0.z, p2); p3 = fmaf(ge, wr0.w, p3);
        }
        {
            float n = fmaf(a.y + bb.y, rs, nmurs);
            n = fmaf(n, g.y, be_.y);
            float ge = gelu_fast(n);
            p0 = fmaf(ge, wr1.x, p0); p1 = fmaf(ge, wr1.y, p1);
            p2 = fmaf(ge, wr1.z, p2); p3 = fmaf(ge, wr1.w, p3);
        }
        {
            float n = fmaf(a.z + bb.z, rs, nmurs);
            n = fmaf(n, g.z, be_.z);
            float ge = gelu_fast(n);
            p0 = fmaf(ge, wr2.x, p0); p1 = fmaf(ge, wr2.y, p1);
            p2 = fmaf(ge, wr2.z, p2); p3 = fmaf(ge, wr2.w, p3);
        }
        {
            float n = fmaf(a.w + bb.w, rs, nmurs);
            n = fmaf(n, g.w, be_.w);
            float ge = gelu_fast(n);
            p0 = fmaf(ge, wr3.x, p0); p1 = fmaf(ge, wr3.y, p1);
            p2 = fmaf(ge, wr3.z, p2); p3 = fmaf(ge, wr3.w, p3);
        }
    }
    float4 b2v = *(const float4*)b2;
    float4 outv = make_float4(p0 + b2v.x, p1 + b2v.y, p2 + b2v.z, p3 + b2v.w);
    ((float4*)logits)[(size_t)(b * NN + i) * NN + j] = outv;
}

// ---------------------------------------------------------------------------
// Kernel C v2 (unchanged): softmax + PV + Wo + residual + LN2; 2 rows/block.
// grid: 2 b x 256 = 512 blocks x 256 thr.
// ---------------------------------------------------------------------------
__global__ __launch_bounds__(256) void kC(
    const float* __restrict__ logits, const float* __restrict__ v,
    const float* __restrict__ Wo,     const float* __restrict__ bo,
    const float* __restrict__ x,      const float* __restrict__ g2,
    const float* __restrict__ b2ln,   float* __restrict__ out)
{
    __shared__ __align__(16) float wl[2][NN * HH];
    __shared__ __align__(16) float sm[2][HH][2];
    __shared__ __align__(16) float out1[2][OUTC];
    __shared__ float redb[4][2][2];

    const int bid = blockIdx.x;
    const int b   = bid >> 8;
    const int i0  = (bid & 255) * 2;
    const int t   = threadIdx.x;

    {
        const float4* src = (const float4*)(logits + ((size_t)b * NN + i0) * NN * HH);
        float4* dst = (float4*)wl;
        #pragma unroll
        for (int k = 0; k < 4; ++k) dst[k * 256 + t] = src[k * 256 + t];
    }
    __syncthreads();

    {
        const int g = t >> 5, k = t & 31;
        const int row = g >> 2, h = g & 3;
        const float* base = wl[row] + h;
        float m = -1e30f;
        #pragma unroll
        for (int mm = 0; mm < 16; ++mm) m = fmaxf(m, base[(k + 32 * mm) * 4]);
        #pragma unroll
        for (int off = 1; off < 32; off <<= 1) m = fmaxf(m, __shfl_xor(m, off, 32));
        float ssum = 0.f;
        #pragma unroll
        for (int mm = 0; mm < 16; ++mm) ssum += __expf(base[(k + 32 * mm) * 4] - m);
        #pragma unroll
        for (int off = 1; off < 32; off <<= 1) ssum += __shfl_xor(ssum, off, 32);
        if (k == 0) { sm[row][h][0] = m; sm[row][h][1] = 1.f / ssum; }
    }
    __syncthreads();

    {
        float* wlf = &wl[0][0];
        #pragma unroll 4
        for (int k = 0; k < 16; ++k) {
            int idx = t + 256 * k;
            int row = idx >> 11, h = idx & 3;
            wlf[idx] = __expf(wlf[idx] - sm[row][h][0]) * sm[row][h][1];
        }
    }
    __syncthreads();

    {
        const int h = t >> 6;
        float a0 = 0.f, a1 = 0.f;
        const float* vb = v + (size_t)b * NN * OUTC + t;
        const float* p0 = wl[0] + h;
        const float* p1 = wl[1] + h;
        #pragma unroll 8
        for (int j = 0; j < NN; ++j) {
            float vv = vb[(size_t)j * OUTC];
            a0 = fmaf(p0[j * 4], vv, a0);
            a1 = fmaf(p1[j * 4], vv, a1);
        }
        out1[0][t] = a0; out1[1][t] = a1;
    }
    __syncthreads();

    {
        float a0 = bo[t], a1 = a0;
        #pragma unroll 4
        for (int c = 0; c < OUTC; ++c) {
            float wv = Wo[(size_t)c * OUTC + t];
            a0 = fmaf(out1[0][c], wv, a0);
            a1 = fmaf(out1[1][c], wv, a1);
        }
        float r0v = a0 + x[((size_t)b * NN + i0    ) * OUTC + t];
        float r1v = a1 + x[((size_t)b * NN + i0 + 1) * OUTC + t];

        const int w = t >> 6, l = t & 63;
        float sv0 = r0v, sq0 = r0v * r0v, sv1 = r1v, sq1 = r1v * r1v;
        #pragma unroll
        for (int off = 1; off < 64; off <<= 1) {
            sv0 += __shfl_xor(sv0, off); sq0 += __shfl_xor(sq0, off);
            sv1 += __shfl_xor(sv1, off); sq1 += __shfl_xor(sq1, off);
        }
        if (l == 0) {
            redb[w][0][0] = sv0; redb[w][0][1] = sq0;
            redb[w][1][0] = sv1; redb[w][1][1] = sq1;
        }
        __syncthreads();
        float gg = g2[t], bb = b2ln[t];
        {
            float sv = redb[0][0][0] + redb[1][0][0] + redb[2][0][0] + redb[3][0][0];
            float sq = redb[0][0][1] + redb[1][0][1] + redb[2][0][1] + redb[3][0][1];
            float mu = sv * (1.f / 256.f);
            float var = sq * (1.f / 256.f) - mu * mu;
            float rsi = rsqrtf(var + LN_EPS);
            out[((size_t)b * NN + i0) * OUTC + t] = (r0v - mu) * rsi * gg + bb;
        }
        {
            float sv = redb[0][1][0] + redb[1][1][0] + redb[2][1][0] + redb[3][1][0];
            float sq = redb[0][1][1] + redb[1][1][1] + redb[2][1][1] + redb[3][1][1];
            float mu = sv * (1.f / 256.f);
            float var = sq * (1.f / 256.f) - mu * mu;
            float rsi = rsqrtf(var + LN_EPS);
            out[((size_t)b * NN + i0 + 1) * OUTC + t] = (r1v - mu) * rsi * gg + bb;
        }
    }
}

// ---------------------------------------------------------------------------
extern "C" void kernel_launch(void* const* d_in, const int* in_sizes, int n_in,
                              void* d_out, int out_size, void* d_ws, size_t ws_size,
                              hipStream_t stream) {
    (void)in_sizes; (void)n_in; (void)out_size; (void)ws_size;
    const float* x    = (const float*)d_in[0];
    const float* We   = (const float*)d_in[1];
    const float* be   = (const float*)d_in[2];
    const float* ln1g = (const float*)d_in[3];
    const float* ln1b = (const float*)d_in[4];
    const float* W2   = (const float*)d_in[5];
    const float* b2   = (const float*)d_in[6];
    const float* Wv   = (const float*)d_in[7];
    const float* bv   = (const float*)d_in[8];
    const float* Wo   = (const float*)d_in[9];
    const float* bo   = (const float*)d_in[10];
    const float* ln2g = (const float*)d_in[11];
    const float* ln2b = (const float*)d_in[12];
    float* out = (float*)d_out;

    float* ws = (float*)d_ws;
    float* hi     = ws + WS_HI;
    float* hj     = ws + WS_HJ;
    float* v      = ws + WS_V;
    float* logits = ws + WS_LOGITS;
    float* cross  = ws + WS_CROSS;
    float* Si     = ws + WS_SI;
    float* SSi    = ws + WS_SSI;
    float* Sj     = ws + WS_SJ;
    float* SSj    = ws + WS_SSJ;

    kA<<<128,  256, 0, stream>>>(x, We, be, Wv, bv, hi, hj, v, Si, SSi, Sj, SSj);
    kX<<<512,  256, 0, stream>>>(hi, hj, cross);
    kB<<<2048, 256, 0, stream>>>(hi, hj, ln1g, ln1b, W2, b2,
                                 Si, SSi, Sj, SSj, cross, logits);
    kC<<<512,  256, 0, stream>>>(logits, v, Wo, bo, x, ln2g, ln2b, out);
}